// Round 4
// baseline (3797.362 us; speedup 1.0000x reference)
//
#include <hip/hip_runtime.h>

// STATE=4096, CDIM=1024, fan_in=5121. RK4 x 4 steps = 16 aug-dynamics evals
// = 64 matvec phases. Persistent kernel (plain launch): both 4096x4096 weight
// matrices live in REGISTERS (64 VGPR each: 512 blocks x 256 thr x 256B),
// converted fp32->bf16 once. __launch_bounds__(256,2) caps VGPR at 256 =>
// 2 blocks/CU x 256 CU = all 512 blocks co-resident (no cooperative API —
// graph-capture-safe). Grid sync: per-block release flag + block-0 aggregate
// + broadcast 'go'. Acquire SPIN-LOADS (no __hip_atomic_fence on this ROCm),
// agent scope => cross-XCD correct per G16.
#define N      4096
#define NC     1024
#define STEPS  4
#define TPB    256
#define NBLK   512

typedef unsigned short us8 __attribute__((ext_vector_type(8)));

__device__ __forceinline__ float bf2f(unsigned short u) {
  union { unsigned int i; float f; } v; v.i = ((unsigned int)u) << 16; return v.f;
}
__device__ __forceinline__ unsigned short f2bf(float f) {
  union { float f; unsigned int i; } v; v.f = f;
  const unsigned int u = v.i;
  return (unsigned short)((u + 0x7FFFu + ((u >> 16) & 1u)) >> 16);  // RNE
}
__device__ __forceinline__ float sigf(float x) { return 1.0f / (1.0f + __expf(-x)); }
__device__ __forceinline__ us8 cvt8(const float4 a, const float4 b) {
  us8 o;
  o[0] = f2bf(a.x); o[1] = f2bf(a.y); o[2] = f2bf(a.z); o[3] = f2bf(a.w);
  o[4] = f2bf(b.x); o[5] = f2bf(b.y); o[6] = f2bf(b.z); o[7] = f2bf(b.w);
  return o;
}

// ---------------------------------------------------------------------------
__global__ __launch_bounds__(TPB) void k_init(const float* __restrict__ h,
                                              const float* __restrict__ b1,
                                              const float* __restrict__ b2,
                                              float* __restrict__ ycur,
                                              float* __restrict__ cp1,
                                              float* __restrict__ cp2,
                                              float* __restrict__ rk,
                                              unsigned* __restrict__ flags) {
  const int j = blockIdx.x * TPB + threadIdx.x;
  if (j < N) { ycur[j] = h[j]; cp1[j] = b1[j]; cp2[j] = b2[j]; }
  if (j < 16) rk[j] = 0.f;
  if (j < 544) flags[j] = 0u;   // 512 arrive-flags + go + pad; re-zero per replay
}

// cp += c @ W[0:NC]  (fp32, once). grid (16, 8, 2), block 256.
__global__ __launch_bounds__(TPB) void k_cpart(const float* __restrict__ W1,
                                               const float* __restrict__ W2,
                                               const float* __restrict__ c,
                                               float* __restrict__ cp1,
                                               float* __restrict__ cp2) {
  const float* __restrict__ W = blockIdx.z ? W2 : W1;
  float* __restrict__ cp = blockIdx.z ? cp2 : cp1;
  __shared__ float xs[128];
  __shared__ float red[8][256];
  const int tid = threadIdx.x;
  const int cb = blockIdx.x, rc = blockIdx.y;
  const int r0 = rc * 128;
  if (tid < 128) xs[tid] = c[r0 + tid];
  __syncthreads();
  const int cg = tid & 31, rg = tid >> 5;
  const float* __restrict__ wbase = W + (size_t)r0 * N + cb * 256 + cg * 8;
  float a[8] = {0,0,0,0,0,0,0,0};
#pragma unroll
  for (int k = 0; k < 16; ++k) {
    const int r = rg + (k << 3);
    const float xv = xs[r];
    const float4 wa = *reinterpret_cast<const float4*>(wbase + (size_t)r * N);
    const float4 wb = *reinterpret_cast<const float4*>(wbase + (size_t)r * N + 4);
    a[0] = fmaf(wa.x, xv, a[0]); a[1] = fmaf(wa.y, xv, a[1]);
    a[2] = fmaf(wa.z, xv, a[2]); a[3] = fmaf(wa.w, xv, a[3]);
    a[4] = fmaf(wb.x, xv, a[4]); a[5] = fmaf(wb.y, xv, a[5]);
    a[6] = fmaf(wb.z, xv, a[6]); a[7] = fmaf(wb.w, xv, a[7]);
  }
#pragma unroll
  for (int e = 0; e < 8; ++e) red[rg][cg * 8 + e] = a[e];
  __syncthreads();
  float ssum = 0.f;
#pragma unroll
  for (int g = 0; g < 8; ++g) ssum += red[g][tid];
  atomicAdd(&cp[cb * 256 + tid], ssum);
}

// ---------------------------------------------------------------------------
// Grid barrier, monotonic rounds. Writers: release-store flag[bid]=round.
// Block 0: acquire-poll all 512 flags (2/thread), then release-store go.
// Others: acquire-spin on go >= round. Acquire on the observing load
// synchronizes-with the release store; block0's go-release transitively
// publishes all blocks' writes. Agent scope => cross-XCD correct (G16).
__device__ __forceinline__ void gsync(unsigned* flags, unsigned* go,
                                      const unsigned round,
                                      const int bid, const int tid) {
  __syncthreads();
  if (bid == 0) {
    if (tid == 0)
      __hip_atomic_store(&flags[0], round, __ATOMIC_RELEASE, __HIP_MEMORY_SCOPE_AGENT);
    while (__hip_atomic_load(&flags[tid], __ATOMIC_ACQUIRE, __HIP_MEMORY_SCOPE_AGENT) < round ||
           __hip_atomic_load(&flags[tid + 256], __ATOMIC_ACQUIRE, __HIP_MEMORY_SCOPE_AGENT) < round) {
      __builtin_amdgcn_s_sleep(1);
    }
    __syncthreads();
    if (tid == 0)
      __hip_atomic_store(go, round, __ATOMIC_RELEASE, __HIP_MEMORY_SCOPE_AGENT);
  } else {
    if (tid == 0) {
      __hip_atomic_store(&flags[bid], round, __ATOMIC_RELEASE, __HIP_MEMORY_SCOPE_AGENT);
      while (__hip_atomic_load(go, __ATOMIC_ACQUIRE, __HIP_MEMORY_SCOPE_AGENT) < round) {
        __builtin_amdgcn_s_sleep(1);
      }
    }
    __syncthreads();
  }
}

// ---------------------------------------------------------------------------
// One phase: reduce previous partials (2 halves x 16 over all 256 threads)
// -> epilogue (per mode, tid<128) -> build x chunk -> matvec from REGISTER
// weights -> write partials.
// Modes: 0=FIRST(x=sig(h)), 1=P2(u1), 2=P3(f,tangent-L1 in), 3=P4(du1,RK),
//        4=PD(df,rk,next-stage x1).
// ---------------------------------------------------------------------------
__device__ __forceinline__ void phase_body(
    const int mode, const us8 (&w)[16], const us8 wrow, const bool doT,
    const float* __restrict__ pin, float* __restrict__ pout,
    const float* __restrict__ cpart,
    float* __restrict__ u1, float* __restrict__ fcur,
    const float* __restrict__ fprev,
    float* __restrict__ ycur, float* __restrict__ ksum,
    float* __restrict__ rk, const int rkIdx, const int s,
    const float csv, const float coef, const float dtv,
    float (&xs)[128], float (&red)[8][256],
    const int tid, const int cb, const int rc, const int j0,
    const int cg, const int rg) {
  // partial reduce split across all 256 threads (red[0..1][0..127] reused)
  if (mode != 0) {
    const int jl = tid & 127, half = tid >> 7;
    const float* __restrict__ pp = pin + ((half << 4) << 12) + j0 + jl;
    float ps = 0.f;
#pragma unroll
    for (int r = 0; r < 16; ++r) ps += pp[(size_t)(r << 12)];
    red[half][jl] = ps;
  }
  __syncthreads();

  if (tid < 128) {
    const int j = j0 + tid;
    float xv;
    if (mode == 0) {                       // FIRST: x1 = sig(h)
      xv = sigf(ycur[j]);
    } else {
      const float ssum = red[0][tid] + red[1][tid];
      if (mode == 1) {                     // P2: u1 = red + cpart1; x2 = sig(u1)
        const float u = ssum + cpart[j];
        if (cb == 0) u1[j] = u;
        xv = sigf(u);
      } else if (mode == 2) {              // P3: f = red + cpart2; v1 = s0'(ys)*f
        const float fv = ssum + cpart[j];
        if (cb == 0) fcur[j] = fv;
        float ys = ycur[j];
        if (csv != 0.f) ys = fmaf(csv * dtv, fprev[j], ys);
        const float s0 = sigf(ys);
        xv = s0 * (1.f - s0) * fv;
      } else if (mode == 3) {              // P4: du1 = red; v2 = s1'(u1)*du1; RK
        if (cb == 0) {
          const float fc = fcur[j];
          if (s == 0)      ksum[j] = fc;
          else if (s < 3)  ksum[j] = fmaf(2.f, fc, ksum[j]);
          else             ycur[j] = fmaf(dtv * (1.f / 6.f), ksum[j] + fc, ycur[j]);
        }
        const float s1 = sigf(u1[j]);
        xv = s1 * (1.f - s1) * ssum;
      } else {                             // PD: df = red; rk += df^2; x1 next
        float v = ssum * ssum;
#pragma unroll
        for (int off = 32; off >= 1; off >>= 1) v += __shfl_down(v, off);
        if (cb == 0 && (tid & 63) == 0) atomicAdd(&rk[rkIdx], v);
        float ys = ycur[j];
        if (csv != 0.f) ys = fmaf(csv * dtv, fprev[j], ys);
        xv = sigf(ys);
      }
    }
    xs[tid] = xv;
  }
  __syncthreads();

  float a[8] = {0,0,0,0,0,0,0,0};
#pragma unroll
  for (int k = 0; k < 16; ++k) {
    const float xv = xs[rg + (k << 3)];
#pragma unroll
    for (int e = 0; e < 8; ++e) a[e] = fmaf(bf2f(w[k][e]), xv, a[e]);
  }
  if (doT) {                               // t-row contribution
#pragma unroll
    for (int e = 0; e < 8; ++e) a[e] = fmaf(bf2f(wrow[e]), coef, a[e]);
  }
#pragma unroll
  for (int e = 0; e < 8; ++e) red[rg][cg * 8 + e] = a[e];
  __syncthreads();
  float ssum = 0.f;
#pragma unroll
  for (int g = 0; g < 8; ++g) ssum += red[g][tid];
  pout[(rc << 12) + cb * 256 + tid] = ssum;
}

// ---------------------------------------------------------------------------
__global__ __launch_bounds__(TPB, 2) void k_ode(
    const float* __restrict__ W1f, const float* __restrict__ W2f,
    const float* __restrict__ tptr,
    float* __restrict__ partA, float* __restrict__ partB,
    const float* __restrict__ cp1, const float* __restrict__ cp2,
    float* __restrict__ u1, float* __restrict__ fb0, float* __restrict__ fb1,
    float* __restrict__ ycur, float* __restrict__ ksum,
    float* __restrict__ rk, unsigned* flags) {
  __shared__ float xs[128];
  __shared__ float red[8][256];
  const int tid = threadIdx.x;
  const int bid = blockIdx.x;
  const int cb = bid & 15, rc = bid >> 4;
  const int j0 = rc * 128;
  const int cg = tid & 31, rg = tid >> 5;
  unsigned* go = flags + 512;

  // ---- one-time: fp32 -> bf16 (RNE) weight tiles into registers ----
  const size_t colOff = (size_t)(cb * 256 + cg * 8);
  const float* __restrict__ w1p = W1f + (size_t)(NC + j0 + rg) * N + colOff;
  const float* __restrict__ w2p = W2f + (size_t)(NC + j0 + rg) * N + colOff;
  us8 w1[16], w2[16];
#pragma unroll 4
  for (int k = 0; k < 16; ++k) {
    const size_t off = (size_t)(k << 3) * N;
    w1[k] = cvt8(*reinterpret_cast<const float4*>(w1p + off),
                 *reinterpret_cast<const float4*>(w1p + off + 4));
    w2[k] = cvt8(*reinterpret_cast<const float4*>(w2p + off),
                 *reinterpret_cast<const float4*>(w2p + off + 4));
  }
  const bool doT = (rc == 31 && rg == 0);
  us8 wt1 = w1[0], wt2 = w2[0];
  if (doT) {
    const float* tp1 = W1f + (size_t)(NC + N) * N + colOff;
    const float* tp2 = W2f + (size_t)(NC + N) * N + colOff;
    wt1 = cvt8(*reinterpret_cast<const float4*>(tp1),
               *reinterpret_cast<const float4*>(tp1 + 4));
    wt2 = cvt8(*reinterpret_cast<const float4*>(tp2),
               *reinterpret_cast<const float4*>(tp2 + 4));
  }
  const float dtv = tptr[0] * (1.0f / STEPS);

  // ---- 16 evals x 4 phases, grid sync between phases ----
  float* pA = partA;
  float* pB = partB;
  unsigned sn = 0;

  for (int i = 0; i < 16; ++i) {
    const int s = i & 3;
    const float csv = (s == 0) ? 0.f : ((s == 3) ? 1.f : 0.5f);
    const float tcoef = ((float)(i >> 2) + csv) * dtv;
    float* fcur = (i & 1) ? fb1 : fb0;
    const float* fprev = (i & 1) ? fb0 : fb1;

    // P1: u1 partials = x1 @ W1_state (FIRST for i=0, PD otherwise)
    phase_body((i == 0) ? 0 : 4, w1, wt1, doT, pB, pA, cp1, u1, fcur, fprev,
               ycur, ksum, rk, i - 1, s, csv, tcoef, dtv, xs, red,
               tid, cb, rc, j0, cg, rg);
    { float* tp = pA; pA = pB; pB = tp; }
    ++sn; gsync(flags, go, sn, bid, tid);

    // P2: f partials = sig(u1+cp1) @ W2_state
    phase_body(1, w2, wt2, doT, pB, pA, cp1, u1, fcur, fprev, ycur, ksum, rk,
               0, s, csv, tcoef, dtv, xs, red, tid, cb, rc, j0, cg, rg);
    { float* tp = pA; pA = pB; pB = tp; }
    ++sn; gsync(flags, go, sn, bid, tid);

    // P3: du1 partials = (sig'(ys)*f) @ W1_state, t-coef 1
    phase_body(2, w1, wt1, doT, pB, pA, cp2, u1, fcur, fprev, ycur, ksum, rk,
               0, s, csv, 1.f, dtv, xs, red, tid, cb, rc, j0, cg, rg);
    { float* tp = pA; pA = pB; pB = tp; }
    ++sn; gsync(flags, go, sn, bid, tid);

    // P4: df partials = (sig'(u1)*du1) @ W2_state, t-coef 1; RK bookkeeping
    phase_body(3, w2, wt2, doT, pB, pA, cp2, u1, fcur, fprev, ycur, ksum, rk,
               0, s, csv, 1.f, dtv, xs, red, tid, cb, rc, j0, cg, rg);
    { float* tp = pA; pA = pB; pB = tp; }
    if (i < 15) { ++sn; gsync(flags, go, sn, bid, tid); }
  }
}

// Reduce the final P4 partials -> rk[15]; copy ycur -> out.
__global__ __launch_bounds__(128) void k_last(const float* __restrict__ part_in,
                                              const float* __restrict__ ycur,
                                              float* __restrict__ rk,
                                              float* __restrict__ out) {
  const int tid = threadIdx.x;
  const int j = blockIdx.x * 128 + tid;
  float df = 0.f;
#pragma unroll 8
  for (int r = 0; r < 32; ++r) df += part_in[(r << 12) + j];
  float v = df * df;
#pragma unroll
  for (int off = 32; off >= 1; off >>= 1) v += __shfl_down(v, off);
  if ((tid & 63) == 0) atomicAdd(&rk[15], v);
  out[j] = ycur[j];
}

__global__ void k_out(const float* __restrict__ rk, const float* __restrict__ tptr,
                      float* __restrict__ out) {
  if (threadIdx.x == 0) {
    const float dtv = tptr[0] * (1.0f / STEPS);
    float r = 0.f;
    for (int st = 0; st < STEPS; ++st)
      r += rk[4 * st] + 2.f * rk[4 * st + 1] + 2.f * rk[4 * st + 2] + rk[4 * st + 3];
    out[N] = r * (dtv / 6.f) * (1.0f / N);
  }
}

// ---------------------------------------------------------------------------
extern "C" void kernel_launch(void* const* d_in, const int* in_sizes, int n_in,
                              void* d_out, int out_size, void* d_ws, size_t ws_size,
                              hipStream_t stream) {
  const float* h  = (const float*)d_in[0];
  const float* t  = (const float*)d_in[1];
  const float* c  = (const float*)d_in[2];
  const float* W1 = (const float*)d_in[3];
  const float* b1 = (const float*)d_in[4];
  const float* W2 = (const float*)d_in[5];
  const float* b2 = (const float*)d_in[6];
  float* out = (float*)d_out;

  // ws: fp32 buffers + flags (~1.2 MB) — weights live in registers.
  float* fp    = (float*)d_ws;
  float* partA = fp;                     // 32*4096
  float* partB = partA + 32 * N;
  float* cp1   = partB + 32 * N;
  float* cp2   = cp1 + N;
  float* u1    = cp2 + N;
  float* fb0   = u1 + N;
  float* fb1   = fb0 + N;
  float* ycur  = fb1 + N;
  float* ksum  = ycur + N;
  float* rk    = ksum + N;               // 16
  unsigned* flags = (unsigned*)(rk + 16); // 512 flags + go + pad

  k_init<<<16, TPB, 0, stream>>>(h, b1, b2, ycur, cp1, cp2, rk, flags);
  k_cpart<<<dim3(16, 8, 2), TPB, 0, stream>>>(W1, W2, c, cp1, cp2);

  k_ode<<<NBLK, TPB, 0, stream>>>(W1, W2, t, partA, partB, cp1, cp2,
                                  u1, fb0, fb1, ycur, ksum, rk, flags);

  k_last<<<32, 128, 0, stream>>>(partB, ycur, rk, out);
  k_out<<<1, 64, 0, stream>>>(rk, t, out);
}